// Round 6
// baseline (543.464 us; speedup 1.0000x reference)
//
#include <hip/hip_runtime.h>

typedef _Float16 f16;
typedef f16 f16x8 __attribute__((ext_vector_type(8)));
typedef float f32x4 __attribute__((ext_vector_type(4)));
typedef float f32x2 __attribute__((ext_vector_type(2)));

static constexpr int NDATA = 50000;
static constexpr int DF    = 3072;
static constexpr int BP    = 256;
static constexpr int NW    = 50688;   // W row stride / padded N (396*128)
static constexpr int NGRPQ = 396;     // k_qk blocks = softmax groups (128 n each)
static constexpr int NDT2  = 48;      // d-tiles of 64 in k_pv

// workspace offsets (bytes)
static constexpr size_t OFF_W  = 0;            // W : 256*50688*2 = 25952256
static constexpr size_t OFF_XH = 25952256;     // xh: 1572864
static constexpr size_t OFF_MP = 27525120;     // Mp: 396*256*4 = 405504
static constexpr size_t OFF_LP = 27930624;     // Lp: 405504
static constexpr size_t OFF_M  = 28336128;     // M : 1024
static constexpr size_t OFF_L  = 28337152;     // L : 1024
static constexpr size_t OFF_P  = 28338176;     // P : nch * 3145728
static constexpr size_t SLAB   = (size_t)BP * DF * 4;

// async global->LDS, 16B per lane; dest = wave-uniform base + lane*16 (HW rule)
__device__ __forceinline__ void dma16(const void* g, void* l) {
  __builtin_amdgcn_global_load_lds(
      (const __attribute__((address_space(1))) void*)(uintptr_t)g,
      (__attribute__((address_space(3))) void*)(uint32_t)(uintptr_t)l,
      16, 0, 0);
}

// lgkm-only barrier: LDS ordered, global loads stay IN FLIGHT
__device__ __forceinline__ void barrier_lgkm() {
  __builtin_amdgcn_sched_barrier(0);
  asm volatile("s_waitcnt lgkmcnt(0)" ::: "memory");
  __builtin_amdgcn_s_barrier();
  __builtin_amdgcn_sched_barrier(0);
}

// ---------------- K1: x -> fp16 ----------------
__global__ void k_prep_x(const float* __restrict__ x, f16* __restrict__ xh) {
  int i = blockIdx.x * 256 + threadIdx.x;
  f32x4 v = ((const f32x4*)x)[i];
  union { f16 f[4]; short4 s; } u;
  u.f[0] = (f16)v[0]; u.f[1] = (f16)v[1]; u.f[2] = (f16)v[2]; u.f[3] = (f16)v[3];
  ((short4*)xh)[i] = u.s;
}

// ---------------- K2: S-tile via MFMA -> block softmax partials + W' ----------------
// tile 128n x 256b, 8 waves, K-step 32. global_load_lds DMA staging, double buffer,
// DMA issued 2 steps ahead, counted vmcnt(4), swizzled source + swizzled reads.
__global__ __launch_bounds__(512, 4) void k_qk(const float* __restrict__ data,
                                               const f16* __restrict__ xh,
                                               const float* __restrict__ sigma,
                                               f16* __restrict__ W,
                                               float* __restrict__ Mp,
                                               float* __restrict__ Lp) {
  __shared__ char smem[66048];
  float* Asm = (float*)smem;                  // 2 x [128][32] fp32 (16 KB each)
  f16*   Bsm = (f16*)(smem + 32768);          // 2 x [256][32] f16  (16 KB each)
  float* dn_s = (float*)(smem + 65536);       // [128]
  float* m4   = (float*)smem;                 // alias: [4][256]
  float* l4   = (float*)(smem + 4096);        // alias: [4][256]
  float* m_s  = (float*)(smem + 8192);        // alias: [256]
  f16*  trans = (f16*)(smem + 20480);         // alias: [256][72] (36.9 KB)

  const int tid = threadIdx.x;
  const int wid = tid >> 6, lane = tid & 63;
  const int l15 = lane & 15, kg = lane >> 4;
  const int wr = wid >> 1, wb = wid & 1;
  const int n0 = blockIdx.x * 128;

  // --- DMA source pointers (per lane; inverse-swizzled chunk so LDS is linear) ---
  // A: inst i covers rows wid*16+i*8 .. +7; lane -> row = R+(lane>>3), chunk = lane&7
  const int rA0 = wid * 16 + (lane >> 3);
  const int rA1 = rA0 + 8;
  const int gA0 = (n0 + rA0) < NDATA ? (n0 + rA0) : NDATA - 1;
  const int gA1 = (n0 + rA1) < NDATA ? (n0 + rA1) : NDATA - 1;
  const float* pA0 = data + (size_t)gA0 * DF + ((lane & 7) ^ (rA0 & 7)) * 4;
  const float* pA1 = data + (size_t)gA1 * DF + ((lane & 7) ^ (rA1 & 7)) * 4;
  // B: inst i covers rows wid*32+i*16 .. +15; lane -> row = R+(lane>>2), chunk = lane&3
  const int rB0 = wid * 32 + (lane >> 2);
  const int rB1 = rB0 + 16;
  const f16* pB0 = xh + (size_t)rB0 * DF + ((lane & 3) ^ ((rB0 >> 1) & 3)) * 8;
  const f16* pB1 = xh + (size_t)rB1 * DF + ((lane & 3) ^ ((rB1 >> 1) & 3)) * 8;
  // DMA LDS bases (wave-uniform)
  float* lA0 = Asm + (size_t)(wid * 16) * 32;
  float* lA1 = Asm + (size_t)(wid * 16 + 8) * 32;
  f16*   lB0 = Bsm + (size_t)(wid * 32) * 32;
  f16*   lB1 = Bsm + (size_t)(wid * 32 + 16) * 32;

  auto issue = [&](int buf, int k0) {
    dma16(pA0 + k0, lA0 + buf * 4096);
    dma16(pA1 + k0, lA1 + buf * 4096);
    dma16(pB0 + k0, lB0 + buf * 8192);
    dma16(pB1 + k0, lB1 + buf * 8192);
  };

  f32x4 acc[2][8] = {};
  float sq0 = 0.f, sq1 = 0.f;
  const int r0 = wr * 32 + l15, r1 = r0 + 16;
  const int sA = l15 & 7;                       // = r0&7 = r1&7
  const int pc0 = (kg * 2) ^ sA, pc1 = (kg * 2 + 1) ^ sA;

  auto compute = [&](int buf) {
    const float* Ab = Asm + buf * 4096;
    const f16*   Bb = Bsm + buf * 8192;
    f32x4 a00 = *(const f32x4*)(Ab + r0 * 32 + pc0 * 4);
    f32x4 a01 = *(const f32x4*)(Ab + r0 * 32 + pc1 * 4);
    f32x4 a10 = *(const f32x4*)(Ab + r1 * 32 + pc0 * 4);
    f32x4 a11 = *(const f32x4*)(Ab + r1 * 32 + pc1 * 4);
    f16x8 af0, af1;
#pragma unroll
    for (int j = 0; j < 4; ++j) {
      af0[j] = (f16)a00[j]; af0[4 + j] = (f16)a01[j];
      af1[j] = (f16)a10[j]; af1[4 + j] = (f16)a11[j];
    }
    if (wb == 0) {
#pragma unroll
      for (int j = 0; j < 4; ++j) {
        sq0 = fmaf(a00[j], a00[j], sq0); sq0 = fmaf(a01[j], a01[j], sq0);
        sq1 = fmaf(a10[j], a10[j], sq1); sq1 = fmaf(a11[j], a11[j], sq1);
      }
    }
#pragma unroll
    for (int c = 0; c < 8; ++c) {
      const int b = wb * 128 + c * 16 + l15;
      f16x8 bf = *(const f16x8*)(Bb + b * 32 + ((kg ^ ((b >> 1) & 3)) * 8));
      acc[0][c] = __builtin_amdgcn_mfma_f32_16x16x32_f16(af0, bf, acc[0][c], 0, 0, 0);
      acc[1][c] = __builtin_amdgcn_mfma_f32_16x16x32_f16(af1, bf, acc[1][c], 0, 0, 0);
    }
  };

  issue(0, 0);
  issue(1, 32);

  for (int k = 0; k < 96; ++k) {
    __builtin_amdgcn_sched_barrier(0);
    if (k < 95) asm volatile("s_waitcnt vmcnt(4)" ::: "memory");  // buf k done, buf k+1 flies
    else        asm volatile("s_waitcnt vmcnt(0)" ::: "memory");
    __builtin_amdgcn_s_barrier();
    __builtin_amdgcn_sched_barrier(0);
    compute(k & 1);
    __builtin_amdgcn_sched_barrier(0);
    asm volatile("s_waitcnt lgkmcnt(0)" ::: "memory");            // my reads retired
    __builtin_amdgcn_s_barrier();                                  // everyone's reads retired
    __builtin_amdgcn_sched_barrier(0);
    if (k + 2 < 96) issue(k & 1, (k + 2) * 32);                   // refill just-freed buffer
  }

  // |d|^2: reduce over the 4 kg quarters (wb==0 waves own it)
  sq0 += __shfl_xor(sq0, 16); sq0 += __shfl_xor(sq0, 32);
  sq1 += __shfl_xor(sq1, 16); sq1 += __shfl_xor(sq1, 32);
  if (wb == 0 && kg == 0) { dn_s[r0] = sq0; dn_s[r1] = sq1; }
  __syncthreads();

  const float sg  = sigma[0];
  const float inv = 0.5f / (sg * sg);
  float dn[2][4];
  bool ok[2][4];
#pragma unroll
  for (int i = 0; i < 2; ++i)
#pragma unroll
    for (int r = 0; r < 4; ++r) {
      int rl = wr * 32 + i * 16 + kg * 4 + r;
      dn[i][r] = dn_s[rl];
      ok[i][r] = (n0 + rl) < NDATA;
    }

  // pass 1: block-local column max
  float pm[8];
#pragma unroll
  for (int c = 0; c < 8; ++c) pm[c] = -1e30f;
#pragma unroll
  for (int i = 0; i < 2; ++i)
#pragma unroll
    for (int r = 0; r < 4; ++r)
#pragma unroll
      for (int c = 0; c < 8; ++c) {
        float v = ok[i][r] ? (2.f * acc[i][c][r] - dn[i][r]) * inv : -1e30f;
        pm[c] = fmaxf(pm[c], v);
      }
#pragma unroll
  for (int c = 0; c < 8; ++c) {
    pm[c] = fmaxf(pm[c], __shfl_xor(pm[c], 16));
    pm[c] = fmaxf(pm[c], __shfl_xor(pm[c], 32));
  }
  if (kg == 0) {
#pragma unroll
    for (int c = 0; c < 8; ++c) m4[wr * 256 + wb * 128 + c * 16 + l15] = pm[c];
  }
  __syncthreads();
  if (tid < 256)
    m_s[tid] = fmaxf(fmaxf(m4[tid], m4[256 + tid]), fmaxf(m4[512 + tid], m4[768 + tid]));
  __syncthreads();

  float mcol[8];
#pragma unroll
  for (int c = 0; c < 8; ++c) mcol[c] = m_s[wb * 128 + c * 16 + l15];

  // pass 2: two 64-n chunks through the trans buffer
  float pl[8] = {};
#pragma unroll
  for (int h = 0; h < 2; ++h) {
    if ((wr >> 1) == h) {
#pragma unroll
      for (int i = 0; i < 2; ++i)
#pragma unroll
        for (int r = 0; r < 4; ++r) {
          const int rl2 = (wr & 1) * 32 + i * 16 + kg * 4 + r;
#pragma unroll
          for (int c = 0; c < 8; ++c) {
            float v = (2.f * acc[i][c][r] - dn[i][r]) * inv;
            float w = ok[i][r] ? __expf(v - mcol[c]) : 0.f;
            pl[c] += w;
            trans[(wb * 128 + c * 16 + l15) * 72 + rl2] = (f16)w;
          }
        }
    }
    __syncthreads();
    {
      const int col = tid >> 1, q = tid & 1;
      const f16* src = trans + col * 72 + q * 32;
      f16* dst = W + (size_t)col * NW + n0 + h * 64 + q * 32;
#pragma unroll
      for (int j = 0; j < 4; ++j)
        *(f16x8*)(dst + j * 8) = *(const f16x8*)(src + j * 8);
    }
    __syncthreads();
  }

#pragma unroll
  for (int c = 0; c < 8; ++c) {
    pl[c] += __shfl_xor(pl[c], 16);
    pl[c] += __shfl_xor(pl[c], 32);
  }
  if (kg == 0) {
#pragma unroll
    for (int c = 0; c < 8; ++c) l4[wr * 256 + wb * 128 + c * 16 + l15] = pl[c];
  }
  __syncthreads();
  if (tid < 256) {
    Mp[blockIdx.x * 256 + tid] = m_s[tid];
    Lp[blockIdx.x * 256 + tid] = l4[tid] + l4[256 + tid] + l4[512 + tid] + l4[768 + tid];
  }
}

// ---------------- K3: combine partials -> M[b], L[b] ----------------
__global__ void k_comb(const float* __restrict__ Mp, const float* __restrict__ Lp,
                       float* __restrict__ M, float* __restrict__ L, int ngrp) {
  __shared__ float ms[4][256], ls[4][256];
  const int tid = threadIdx.x;
  const int q = tid >> 8, b = tid & 255;
  float m = -1e38f, l = 0.f;
  for (int g = q; g < ngrp; g += 4) {
    float m2 = Mp[g * 256 + b], l2 = Lp[g * 256 + b];
    if (m2 > m) { l = l * __expf(m - m2) + l2; m = m2; }
    else        { l += l2 * __expf(m2 - m); }
  }
  ms[q][b] = m; ls[q][b] = l;
  __syncthreads();
  if (q == 0) {
#pragma unroll
    for (int j = 1; j < 4; ++j) {
      float m2 = ms[j][b], l2 = ls[j][b];
      if (m2 > m) { l = l * __expf(m - m2) + l2; m = m2; }
      else        { l += l2 * __expf(m2 - m); }
    }
    M[b] = m; L[b] = l;
  }
}

// ---------------- K4: eps partials = (W*exp(Mp-M)) @ data, split-K over n ----------------
// 512 thr, tile 256b x 64d, K-step 32. Pair-packed staging (2x ds_write_b32/thread).
__global__ __launch_bounds__(512, 4) void k_pv(const float* __restrict__ data,
                                               const f16* __restrict__ W,
                                               const float* __restrict__ Mp,
                                               const float* __restrict__ M,
                                               float* __restrict__ part,
                                               int chn, int per8) {
  __shared__ f16 T[2][64 * 40];   // [d][n(32)+pad]
  const int tid = threadIdx.x;
  const int wid = tid >> 6, lane = tid & 63;
  const int l15 = lane & 15, kg = lane >> 4;
  const int bid = blockIdx.x;
  const int swz = (bid & 7) * per8 + (bid >> 3);   // XCD-chunked (grid % 8 == 0)
  const int chunk = swz / NDT2;
  const int dt = swz % NDT2;
  const int d0 = dt * 64;
  const int nstart = chunk * chn;
  const int kst = chn >> 5;
  const int np = tid >> 5;           // n-pair 0..15
  const int d2 = (tid & 31) * 2;     // d (even) 0..62

  f32x4 acc[2][4] = {};
  const int b0 = wid * 32 + l15, b1 = b0 + 16;
  const float Mb0 = M[b0], Mb1 = M[b1];
  const f16* wp0 = W + (size_t)b0 * NW + nstart + kg * 8;
  const f16* wp1 = W + (size_t)b1 * NW + nstart + kg * 8;

  f32x2 gaA, gbA, gaB, gbB;
  f16x8 w0c, w1c, w0n, w1n;
  float mpAc, mpBc, mpAn, mpBn;

  auto gload = [&](int ks, f32x2& ga, f32x2& gb) {
    int n = nstart + ks * 32 + np * 2;
    int na = n < NDATA ? n : NDATA - 1;          // tail rows have W==0
    int nb = (n + 1) < NDATA ? (n + 1) : NDATA - 1;
    ga = *(const f32x2*)(data + (size_t)na * DF + d0 + d2);
    gb = *(const f32x2*)(data + (size_t)nb * DF + d0 + d2);
  };
  auto wload = [&](int ks, f16x8& w0, f16x8& w1, float& ma, float& mb) {
    w0 = *(const f16x8*)(wp0 + ks * 32);
    w1 = *(const f16x8*)(wp1 + ks * 32);
    int gq = (nstart + ks * 32) >> 7;
    ma = Mp[gq * 256 + b0];
    mb = Mp[gq * 256 + b1];
  };
  auto twrite = [&](int buf, f32x2& ga, f32x2& gb) {
    uint32_t* Tw = (uint32_t*)&T[buf][0];
    int pn = np ^ (((d2 >> 3) & 3) << 2);        // pair-unit bank swizzle
    union { f16 f[2]; uint32_t u; } u0, u1;
    u0.f[0] = (f16)ga[0]; u0.f[1] = (f16)gb[0];  // n, n+1 at d
    u1.f[0] = (f16)ga[1]; u1.f[1] = (f16)gb[1];  // n, n+1 at d+1
    Tw[d2 * 20 + pn] = u0.u;
    Tw[(d2 + 1) * 20 + pn] = u1.u;
  };
  auto compute = [&](int buf, f16x8& w0, f16x8& w1, float ma, float mb) {
    f16 h0 = (f16)__expf(ma - Mb0);
    f16 h1 = (f16)__expf(mb - Mb1);
    f16x8 a0, a1;
#pragma unroll
    for (int j = 0; j < 8; ++j) { a0[j] = w0[j] * h0; a1[j] = w1[j] * h1; }
#pragma unroll
    for (int c = 0; c < 4; ++c) {
      int d = c * 16 + l15;
      int pb = (kg * 8) ^ (((d >> 3) & 3) << 3);
      f16x8 bf = *(const f16x8*)(&T[buf][d * 40 + pb]);
      acc[0][c] = __builtin_amdgcn_mfma_f32_16x16x32_f16(a0, bf, acc[0][c], 0, 0, 0);
      acc[1][c] = __builtin_amdgcn_mfma_f32_16x16x32_f16(a1, bf, acc[1][c], 0, 0, 0);
    }
  };

  gload(0, gaA, gbA);
  wload(0, w0c, w1c, mpAc, mpBc);
  twrite(0, gaA, gbA);
  gload(1, gaB, gbB);
  barrier_lgkm();

  for (int ks = 0; ks < kst; ks += 2) {
    if (ks + 2 < kst) gload(ks + 2, gaA, gbA);
    if (ks + 1 < kst) wload(ks + 1, w0n, w1n, mpAn, mpBn);
    compute(0, w0c, w1c, mpAc, mpBc);
    if (ks + 1 < kst) twrite(1, gaB, gbB);
    barrier_lgkm();
    if (ks + 1 < kst) {
      if (ks + 3 < kst) gload(ks + 3, gaB, gbB);
      if (ks + 2 < kst) wload(ks + 2, w0c, w1c, mpAc, mpBc);
      compute(1, w0n, w1n, mpAn, mpBn);
      if (ks + 2 < kst) twrite(0, gaA, gbA);
      barrier_lgkm();
    }
  }

  float* pp = part + (size_t)chunk * (BP * DF);
#pragma unroll
  for (int i = 0; i < 2; ++i)
#pragma unroll
    for (int c = 0; c < 4; ++c)
#pragma unroll
      for (int r = 0; r < 4; ++r) {
        int b = wid * 32 + i * 16 + kg * 4 + r;
        int d = d0 + c * 16 + l15;
        pp[(size_t)b * DF + d] = acc[i][c][r];
      }
}

// ---------------- K5: out = (x - (sum partials)/L) / sigma ----------------
__global__ void k_final(const float* __restrict__ x, const float* __restrict__ sigma,
                        const float* __restrict__ part, const float* __restrict__ L,
                        float* __restrict__ out, int nch) {
  int i = blockIdx.x * 256 + threadIdx.x;
  int b = (i * 4) / DF;
  f32x4 s = {};
  for (int c = 0; c < nch; ++c) s += ((const f32x4*)(part + (size_t)c * BP * DF))[i];
  f32x4 xv = ((const f32x4*)x)[i];
  float invL = 1.f / L[b];
  float invsg = 1.f / sigma[0];
  f32x4 r;
#pragma unroll
  for (int j = 0; j < 4; ++j) r[j] = (xv[j] - s[j] * invL) * invsg;
  ((f32x4*)out)[i] = r;
}

extern "C" void kernel_launch(void* const* d_in, const int* in_sizes, int n_in,
                              void* d_out, int out_size, void* d_ws, size_t ws_size,
                              hipStream_t stream) {
  const float* x     = (const float*)d_in[0];
  const float* sigma = (const float*)d_in[1];
  const float* data  = (const float*)d_in[2];
  float* out = (float*)d_out;
  char* ws = (char*)d_ws;

  f16*   W  = (f16*)(ws + OFF_W);
  f16*   xh = (f16*)(ws + OFF_XH);
  float* Mp = (float*)(ws + OFF_MP);
  float* Lp = (float*)(ws + OFF_LP);
  float* M  = (float*)(ws + OFF_M);
  float* L  = (float*)(ws + OFF_L);
  float* P  = (float*)(ws + OFF_P);

  int nch = 24, chn = 2112;                         // 24*2112 = 50688 exactly
  if (ws_size < OFF_P + 24 * SLAB) { nch = 16; chn = 3168; }
  if (ws_size < OFF_P + 16 * SLAB) { nch = 8;  chn = 6336; }
  const int grid_pv = NDT2 * nch;
  const int per8 = grid_pv / 8;

  k_prep_x<<<768, 256, 0, stream>>>(x, xh);
  k_qk<<<NGRPQ, 512, 0, stream>>>(data, xh, sigma, W, Mp, Lp);
  k_comb<<<1, 1024, 0, stream>>>(Mp, Lp, M, L, NGRPQ);
  k_pv<<<grid_pv, 512, 0, stream>>>(data, W, Mp, M, P, chn, per8);
  k_final<<<768, 256, 0, stream>>>(x, sigma, P, L, out, nch);
}